// Round 14
// baseline (133.630 us; speedup 1.0000x reference)
//
#include <hip/hip_runtime.h>

// ---------------------------------------------------------------------------
// MultiheadSelfAttention: x[2,2048,1024] f32, w_qkv[3072,1024] f32,
// w_out[1024,1024] f32 -> out[2,2048,1024] f32.
// cast->bf16; qkv = x @ w_qkv^T via 256x256 fine-interleaved 4-phase GEMM
// (K-half LDS, per-phase half-tile staging, counted vmcnt(4), 2 barriers/phase,
// m201-style); V pre-transpose; causal flash attn (round-7 structure);
// out = ctx @ w_out^T via 128x128 GEMM. fp32 accumulation.
// ---------------------------------------------------------------------------

typedef short short8 __attribute__((ext_vector_type(8)));
typedef float f32x4 __attribute__((ext_vector_type(4)));
typedef unsigned short u16;
typedef unsigned int u32;

#define T_SEQ 2048
#define N_B 2
#define N_H 16
#define HD 64
#define DM 1024
#define TRIPLE 3072

__device__ __forceinline__ u16 f2bf(float f) {
  union { float f; unsigned u; } v;
  v.f = f;
  unsigned r = v.u + 0x7fffu + ((v.u >> 16) & 1u);
  return (u16)(r >> 16);
}

__device__ __forceinline__ float bf2f(u16 x) {
  return __uint_as_float((u32)x << 16);
}

__device__ __forceinline__ u32 cvtpk(float a, float b) {
  u32 r;
  asm("v_cvt_pk_bf16_f32 %0, %1, %2" : "=v"(r) : "v"(a), "v"(b));
  return r;
}

typedef const __attribute__((address_space(1))) void gvoid;
typedef __attribute__((address_space(3))) void lvoid;

__device__ __forceinline__ void g2l16(const void* g, void* l) {
  __builtin_amdgcn_global_load_lds((gvoid*)g, (lvoid*)l, 16, 0, 0);
}

__device__ __forceinline__ void storeC(float* p, float v) { *p = v; }
__device__ __forceinline__ void storeC(u16* p, float v) { *p = f2bf(v); }

// ---------------------------------------------------------------------------
// fused cast of x | w_qkv | w_out into contiguous bf16 workspace
__global__ __launch_bounds__(256) void cast_all(const float4* __restrict__ x,
                                                const float4* __restrict__ wq,
                                                const float4* __restrict__ wo,
                                                ushort4* __restrict__ out) {
  int i = blockIdx.x * 256 + threadIdx.x;
  const float4* src;
  int off;
  if (i < 1048576) { src = x; off = 0; }
  else if (i < 1835008) { src = wq; off = 1048576; }
  else { src = wo; off = 1835008; }
  float4 v = src[i - off];
  ushort4 o;
  o.x = f2bf(v.x); o.y = f2bf(v.y); o.z = f2bf(v.z); o.w = f2bf(v.w);
  out[i] = o;
}

// ---------------------------------------------------------------------------
// V transpose: qkv[b*T+t][2048 + h*64 + d] -> vT[(b*16+h)*64 + d][t] (bf16).
// ---------------------------------------------------------------------------
__global__ __launch_bounds__(256) void vtrans(const u16* __restrict__ qkv,
                                              u16* __restrict__ vT) {
  const int tid = threadIdx.x;
  const int w = tid >> 6, lane = tid & 63;
  const int ti = lane >> 3, di = lane & 7;
  const int h = blockIdx.y, b = blockIdx.z;
  const int t0 = blockIdx.x * 256 + w * 64 + ti * 8;

  const u16* src = qkv + (size_t)(b * T_SEQ + t0) * TRIPLE + 2 * DM + h * HD + di * 8;
  u32 x[8][4];
#pragma unroll
  for (int e = 0; e < 8; ++e) {
    union { short8 v; u32 u[4]; } cv;
    cv.v = *(const short8*)(src + (size_t)e * TRIPLE);
#pragma unroll
    for (int j = 0; j < 4; ++j) x[e][j] = cv.u[j];
  }
  u32 y[8][4];
#pragma unroll
  for (int a = 0; a < 4; ++a)
#pragma unroll
    for (int j = 0; j < 4; ++j) {
      u32 lo = x[2 * a][j], hi = x[2 * a + 1][j];
      y[2 * a][j] = (lo & 0x0000FFFFu) | (hi << 16);
      y[2 * a + 1][j] = (lo >> 16) | (hi & 0xFFFF0000u);
    }
  u16* dst = vT + ((size_t)(b * N_H + h) * HD + di * 8) * T_SEQ + t0;
#pragma unroll
  for (int dd = 0; dd < 8; ++dd) {
    union { short8 v; u32 u[4]; } cv;
#pragma unroll
    for (int a = 0; a < 4; ++a) cv.u[a] = y[2 * a + (dd & 1)][dd >> 1];
    *(short8*)(dst + (size_t)dd * T_SEQ) = cv.v;
  }
}

// ---------------------------------------------------------------------------
// 256x256 tile, BK=64, 8 waves (2M x 4N), fine-interleaved 4-phase schedule:
// per phase {8 ds_read_b128; stage ONE half-tile (2 g2l16); vmcnt(4) at odd
// phases; s_barrier; lgkmcnt(0); 16 MFMA; s_barrier}. Double-buffered LDS
// stored as [buf][mat][K-half][256 rows][32 K] (128 KB). Loads stay in
// flight across barriers (counted vmcnt). C = A * W^T, bf16 in / fp32 acc.
// ---------------------------------------------------------------------------
template <typename OutT>
__global__ __launch_bounds__(512, 2) void gemm_bt_256(const u16* __restrict__ A,
                                                      const u16* __restrict__ W,
                                                      OutT* __restrict__ C,
                                                      int M, int N, int K) {
  __shared__ char Ls[2][2][2][16384];   // [buf][mat][Kh]: 256 rows x 32 K bf16

  const int tid = threadIdx.x;
  const int lane = tid & 63, w = tid >> 6;
  const int l15 = lane & 15, l4 = lane >> 4;
  const int wm = w >> 2, wn = w & 3;          // 2 x 4 wave grid
  const int m0 = blockIdx.y * 256, n0 = blockIdx.x * 256;

  // staging geometry: chunk c in [0,1024) per (mat,Kh): row = c>>2, slot = c&3
  // content of slot s of row r = source K-chunk s ^ swz(r), swz(r)=((r>>1)^(r>>3))&3
  const int c0 = tid, c1 = 512 + tid;
  const int r0 = c0 >> 2, r1 = c1 >> 2;
  const int k0off = ((c0 & 3) ^ (((r0 >> 1) ^ (r0 >> 3)) & 3)) << 3;
  const int k1off = ((c1 & 3) ^ (((r1 >> 1) ^ (r1 >> 3)) & 3)) << 3;
  const u16* A0 = A + (size_t)(m0 + r0) * K + k0off;
  const u16* A1 = A + (size_t)(m0 + r1) * K + k1off;
  const u16* B0 = W + (size_t)(n0 + r0) * K + k0off;
  const u16* B1 = W + (size_t)(n0 + r1) * K + k1off;

#define STAGEH(mat_, kh_, kt_, buf_)                                           \
  {                                                                            \
    const int ko_ = (kt_) * 64 + (kh_) * 32;                                   \
    if ((mat_) == 0) {                                                         \
      g2l16(A0 + ko_, Ls[buf_][0][kh_] + tid * 16);                            \
      g2l16(A1 + ko_, Ls[buf_][0][kh_] + (512 + tid) * 16);                    \
    } else {                                                                   \
      g2l16(B0 + ko_, Ls[buf_][1][kh_] + tid * 16);                            \
      g2l16(B1 + ko_, Ls[buf_][1][kh_] + (512 + tid) * 16);                    \
    }                                                                          \
  }

  const f32x4 zero = {0.f, 0.f, 0.f, 0.f};
  f32x4 acc[8][4];
#pragma unroll
  for (int am = 0; am < 8; ++am)
#pragma unroll
    for (int n = 0; n < 4; ++n) acc[am][n] = zero;

  const int nkt = K >> 6;

  // prologue: tile 0, all 4 halves into buf 0; wait for K-half 0 pair only
  STAGEH(0, 0, 0, 0);
  STAGEH(1, 0, 0, 0);
  STAGEH(0, 1, 0, 0);
  STAGEH(1, 1, 0, 0);
  asm volatile("s_waitcnt vmcnt(4)" ::: "memory");
  __builtin_amdgcn_s_barrier();

  for (int kt = 0; kt < nkt; ++kt) {
    const int cur = kt & 1;
    const bool notlast = (kt + 1 < nkt);

#pragma unroll
    for (int ph = 0; ph < 4; ++ph) {
      const int kk = ph >> 1, mh = ph & 1;

      // ---- 8 ds_read_b128 (data guaranteed by the previous barrier) ----
      short8 a[4], b[4];
#pragma unroll
      for (int m = 0; m < 4; ++m) {
        int row = wm * 128 + mh * 64 + m * 16 + l15;
        int slot = l4 ^ (((row >> 1) ^ (row >> 3)) & 3);
        a[m] = *(const short8*)(Ls[cur][0][kk] + row * 64 + (slot << 4));
      }
#pragma unroll
      for (int n = 0; n < 4; ++n) {
        int row = wn * 64 + n * 16 + l15;
        int slot = l4 ^ (((row >> 1) ^ (row >> 3)) & 3);
        b[n] = *(const short8*)(Ls[cur][1][kk] + row * 64 + (slot << 4));
      }

      // ---- stage one half-tile of tile kt+1 (ph0:A-Kh0 ph1:B-Kh0 ph2:A-Kh1
      //      ph3:B-Kh1), counted vmcnt at odd phases ----
      if (notlast) {
        STAGEH(ph & 1, ph >> 1, kt + 1, cur ^ 1);
        if (ph & 1) asm volatile("s_waitcnt vmcnt(4)" ::: "memory");
      } else {
        if (ph == 1) asm volatile("s_waitcnt vmcnt(0)" ::: "memory");
      }
      __builtin_amdgcn_s_barrier();
      asm volatile("s_waitcnt lgkmcnt(0)" ::: "memory");
      __builtin_amdgcn_sched_barrier(0);

      __builtin_amdgcn_s_setprio(1);
#pragma unroll
      for (int m = 0; m < 4; ++m)
#pragma unroll
        for (int n = 0; n < 4; ++n)
          acc[mh * 4 + m][n] =
              __builtin_amdgcn_mfma_f32_16x16x32_bf16(a[m], b[n], acc[mh * 4 + m][n], 0, 0, 0);
      __builtin_amdgcn_s_setprio(0);
      __builtin_amdgcn_s_barrier();
    }
  }
#undef STAGEH

  // epilogue
#pragma unroll
  for (int am = 0; am < 8; ++am)
#pragma unroll
    for (int n = 0; n < 4; ++n)
#pragma unroll
      for (int r = 0; r < 4; ++r) {
        int row = m0 + wm * 128 + (am >> 2) * 64 + (am & 3) * 16 + l4 * 4 + r;
        int col = n0 + wn * 64 + n * 16 + l15;
        storeC(C + (size_t)row * N + col, acc[am][n][r]);
      }
}

// ---------------------------------------------------------------------------
// 128x128 tile GEMM (m97 structure) — used for the output projection.
// ---------------------------------------------------------------------------
template <typename OutT>
__global__ __launch_bounds__(256) void gemm_bt(const u16* __restrict__ A,
                                               const u16* __restrict__ W,
                                               OutT* __restrict__ C,
                                               int M, int N, int K) {
  __shared__ char As[128 * 64 * 2];
  __shared__ char Bs[128 * 64 * 2];
  const int tid = threadIdx.x;
  const int lane = tid & 63, w = tid >> 6;
  const int l15 = lane & 15, l4 = lane >> 4;
  const int m0 = blockIdx.y * 128, n0 = blockIdx.x * 128;
  const int wr = (w >> 1) * 64, wc = (w & 1) * 64;

  const f32x4 zero = {0.f, 0.f, 0.f, 0.f};
  f32x4 acc[4][4];
#pragma unroll
  for (int m = 0; m < 4; ++m)
#pragma unroll
    for (int n = 0; n < 4; ++n) acc[m][n] = zero;

  for (int k0 = 0; k0 < K; k0 += 64) {
#pragma unroll
    for (int i = 0; i < 4; ++i) {
      const int cb = (i * 4 + w) * 64;
      const int c = cb + lane;
      const int row = c >> 3;
      const int ks = ((c & 7) ^ (row & 7)) * 8;
      g2l16(A + (size_t)(m0 + row) * K + k0 + ks, As + (size_t)cb * 16);
      g2l16(W + (size_t)(n0 + row) * K + k0 + ks, Bs + (size_t)cb * 16);
    }
    __syncthreads();

#pragma unroll
    for (int kk = 0; kk < 2; ++kk) {
      short8 a[4], b[4];
#pragma unroll
      for (int m = 0; m < 4; ++m) {
        int row = wr + m * 16 + l15;
        int slot = (kk * 4 + l4) ^ (row & 7);
        a[m] = *(const short8*)(As + row * 128 + slot * 16);
      }
#pragma unroll
      for (int n = 0; n < 4; ++n) {
        int row = wc + n * 16 + l15;
        int slot = (kk * 4 + l4) ^ (row & 7);
        b[n] = *(const short8*)(Bs + row * 128 + slot * 16);
      }
#pragma unroll
      for (int m = 0; m < 4; ++m)
#pragma unroll
        for (int n = 0; n < 4; ++n)
          acc[m][n] = __builtin_amdgcn_mfma_f32_16x16x32_bf16(a[m], b[n], acc[m][n], 0, 0, 0);
    }
    __syncthreads();
  }

#pragma unroll
  for (int m = 0; m < 4; ++m)
#pragma unroll
    for (int n = 0; n < 4; ++n)
#pragma unroll
      for (int r = 0; r < 4; ++r) {
        int row = m0 + wr + m * 16 + l4 * 4 + r;
        int col = n0 + wc + n * 16 + l15;
        storeC(C + (size_t)row * N + col, acc[m][n][r]);
      }
}

// ---------------------------------------------------------------------------
// Causal flash attention (round-7 structure, best measured). 8-wave blocks,
// 128 q-rows per pass, paired q-tiles (p, 15-p). Pass A: kt = 0..2p+1
// ascending (diag last). Pass B: kt = 31-2p..0 descending (diag first).
// 34 iterations for every block. Triple-buffered K/V staged by
// global_load_lds with 2-deep prefetch; barriers use counted vmcnt(2).
// Grid: x = (b,h) group (XCD colocation), y = p.
// ---------------------------------------------------------------------------
__global__ __launch_bounds__(512) void attn_fwd(const u16* __restrict__ qkv,
                                                const u16* __restrict__ vT,
                                                u16* __restrict__ ctx) {
  __shared__ char Ks[3][8192];   // K tile [64 key][8 slots x 16B], slot=c^(row&7)
  __shared__ char Vs[3][8192];   // V^T tile [64 d][8 slots x 16B], slot=c^(d&7)
  __shared__ char Pl[8][2048];   // per-wave P [16 q][64 key], swizzled

  const int tid = threadIdx.x;
  const int lane = tid & 63, w = tid >> 6;        // w in 0..7
  const int l15 = lane & 15, l4 = lane >> 4;
  const int g = blockIdx.x;                       // b*16+h : same-XCD group
  const int p = blockIdx.y;                       // 0..7
  const int h = g & 15, b = g >> 4;
  const int q0A = 128 * p, q0B = 128 * (15 - p);
  const int nA = 2 * p + 2;                       // pass-A iterations; total 34

  // ---- preload Q for BOTH passes, prescaled by 0.125*log2(e) ----
  const float c_log2 = 0.18033688011112042f;
  short8 qa2[2][2];
#pragma unroll
  for (int ps = 0; ps < 2; ++ps) {
    const int qq0 = ps ? q0B : q0A;
    const u16* qp = qkv + (size_t)(b * T_SEQ + qq0 + w * 16 + l15) * TRIPLE + h * HD;
#pragma unroll
    for (int kk = 0; kk < 2; ++kk) {
      short8 raw = *(const short8*)(qp + kk * 32 + l4 * 8);
      union { short8 v; u32 w4[4]; } qq;
#pragma unroll
      for (int j = 0; j < 4; ++j)
        qq.w4[j] = cvtpk(bf2f((u16)raw[2 * j]) * c_log2,
                         bf2f((u16)raw[2 * j + 1]) * c_log2);
      qa2[ps][kk] = qq.v;
    }
  }

  // ---- staging bases (pre-swizzled source, linear LDS dest) ----
  const int r0 = tid >> 3, c0 = tid & 7;          // r0: 0..63 (512 threads)
  const int swz = (c0 ^ (r0 & 7)) << 3;
  const u16* kbase = qkv + (size_t)(b * T_SEQ + r0) * TRIPLE + DM + h * HD + swz;
  const u16* vbase = vT + ((size_t)g * HD + r0) * T_SEQ + swz;

#define STAGE(kt_, buf_)                                                     \
  {                                                                          \
    g2l16(kbase + (size_t)((kt_) * (64 * TRIPLE)), Ks[buf_] + tid * 16);     \
    g2l16(vbase + (u32)((kt_) * 64), Vs[buf_] + tid * 16);                   \
  }

  char* Plb = Pl[w];

  const f32x4 zero = {0.f, 0.f, 0.f, 0.f};
  f32x4 o[4];
#pragma unroll
  for (int nt = 0; nt < 4; ++nt) o[nt] = zero;
  float mr = -INFINITY, lr = 0.f;
  short8 qa0 = qa2[0][0], qa1 = qa2[0][1];
  int q0 = q0A;

  // ---- prologue: stage seq 0,1 into bufs 0,1; wait seq0 only ----
  STAGE(0, 0);
  STAGE(1, 1);
  asm volatile("s_waitcnt vmcnt(2)\n\ts_barrier" ::: "memory");

  int cur = 0;
  for (int i = 0;; ++i) {
    const int kt = (i < nA) ? i : 33 - i;

    // ---- issue 2-ahead prefetch into buf (cur+2)%3 ----
    if (i + 2 < 34) {
      const int kt2 = (i + 2 < nA) ? (i + 2) : 31 - i;
      int sb = cur - 1;
      if (sb < 0) sb = 2;
      STAGE(kt2, sb);
    }

    const int k0 = kt * 64;
    // wave-active guard: skip tiles entirely above this wave's q-band
    if (k0 <= q0 + w * 16) {
      // ---- S^T = K Q^T : lane holds S[key=mt*16+l4*4+r][q=l15] ----
      f32x4 s[4];
#pragma unroll
      for (int mt = 0; mt < 4; ++mt) s[mt] = zero;
      __builtin_amdgcn_s_setprio(1);
#pragma unroll
      for (int mt = 0; mt < 4; ++mt) {
        int row = mt * 16 + l15;
        int slot0 = l4 ^ (row & 7);
        short8 kb0 = *(const short8*)(Ks[cur] + row * 128 + slot0 * 16);
        s[mt] = __builtin_amdgcn_mfma_f32_16x16x32_bf16(kb0, qa0, s[mt], 0, 0, 0);
        int slot1 = (4 + l4) ^ (row & 7);
        short8 kb1 = *(const short8*)(Ks[cur] + row * 128 + slot1 * 16);
        s[mt] = __builtin_amdgcn_mfma_f32_16x16x32_bf16(kb1, qa1, s[mt], 0, 0, 0);
      }
      __builtin_amdgcn_s_setprio(0);

      // causal mask near the diagonal (Q pre-scaled; S in log2 units)
      if (i >= nA - 2 && i <= nA + 1) {
        const int qrow = q0 + w * 16 + l15;
#pragma unroll
        for (int mt = 0; mt < 4; ++mt)
#pragma unroll
          for (int r = 0; r < 4; ++r) {
            int key = k0 + mt * 16 + l4 * 4 + r;
            if (key > qrow) s[mt][r] = -INFINITY;
          }
      }

      // ---- online softmax, defer-max (THR = 8 in log2 units) ----
      float mx = fmaxf(fmaxf(fmaxf(s[0][0], s[0][1]), fmaxf(s[0][2], s[0][3])),
                       fmaxf(fmaxf(s[1][0], s[1][1]), fmaxf(s[1][2], s[1][3])));
      mx = fmaxf(mx, fmaxf(fmaxf(fmaxf(s[2][0], s[2][1]), fmaxf(s[2][2], s[2][3])),
                           fmaxf(fmaxf(s[3][0], s[3][1]), fmaxf(s[3][2], s[3][3]))));
      mx = fmaxf(mx, __shfl_xor(mx, 16));
      mx = fmaxf(mx, __shfl_xor(mx, 32));
      if (!__all(mx - mr <= 8.0f)) {
        float mn = fmaxf(mr, mx);
        float fr = exp2f(mr - mn);   // 0 on first active tile of a pass
        lr *= fr;
#pragma unroll
        for (int r = 0; r < 4; ++r) {
          float frq = __shfl(fr, l4 * 4 + r);
#pragma unroll
          for (int nt = 0; nt < 4; ++nt) o[nt][r] *= frq;
        }
        mr = mn;
      }
      float ps = 0.f;
#pragma unroll
      for (int mt = 0; mt < 4; ++mt)
#pragma unroll
        for (int r = 0; r < 4; ++r) {
          float pv = exp2f(s[mt][r] - mr);
          s[mt][r] = pv;
          ps += pv;
        }
      lr += ps;   // per-lane partial; reduced at pass epilogue

      // ---- P -> per-wave LDS (cvt_pk + b64 writes) ----
#pragma unroll
      for (int mt = 0; mt < 4; ++mt) {
        uint2 pw;
        pw.x = cvtpk(s[mt][0], s[mt][1]);
        pw.y = cvtpk(s[mt][2], s[mt][3]);
        int slot = ((mt * 2 + (l4 >> 1)) ^ (l15 & 7));
        *(uint2*)(Plb + l15 * 128 + (slot << 4) + ((l4 & 1) << 3)) = pw;
      }

      // ---- PV: o[q][d] += P[q][key] * V^T[d][key] ----
      __builtin_amdgcn_s_setprio(1);
#pragma unroll
      for (int kk = 0; kk < 2; ++kk) {
        short8 pa = *(const short8*)(Plb + l15 * 128 + (((kk * 4 + l4) ^ (l15 & 7)) << 4));
#pragma unroll
        for (int nt = 0; nt < 4; ++nt) {
          int d = nt * 16 + l15;
          int slot = (kk * 4 + l4) ^ (l15 & 7);
          short8 vb = *(const short8*)(Vs[cur] + d * 128 + slot * 16);
          o[nt] = __builtin_amdgcn_mfma_f32_16x16x32_bf16(pa, vb, o[nt], 0, 0, 0);
        }
      }
      __builtin_amdgcn_s_setprio(0);
    }

    // ---- pass epilogues ----
    if (i == nA - 1 || i == 33) {
      lr += __shfl_xor(lr, 16);
      lr += __shfl_xor(lr, 32);
#pragma unroll
      for (int r = 0; r < 4; ++r) {
        float lrq = __shfl(lr, l4 * 4 + r);
        float inv = __builtin_amdgcn_rcpf(lrq);
        size_t t = (size_t)(b * T_SEQ + q0 + w * 16 + l4 * 4 + r);
#pragma unroll
        for (int nt = 0; nt < 4; ++nt)
          ctx[t * DM + h * HD + nt * 16 + l15] = f2bf(o[nt][r] * inv);
      }
      if (i == 33) break;
      // reset for pass B
#pragma unroll
      for (int nt = 0; nt < 4; ++nt) o[nt] = zero;
      mr = -INFINITY; lr = 0.f;
      qa0 = qa2[1][0]; qa1 = qa2[1][1];
      q0 = q0B;
    }

    // ---- counted-vmcnt barrier: keep newest stage (2 loads) in flight ----
    if (i == 32)
      asm volatile("s_waitcnt vmcnt(0)\n\ts_barrier" ::: "memory");
    else
      asm volatile("s_waitcnt vmcnt(2)\n\ts_barrier" ::: "memory");
    cur = (cur == 2) ? 0 : cur + 1;
  }
#undef STAGE
}

// ---------------------------------------------------------------------------
extern "C" void kernel_launch(void* const* d_in, const int* in_sizes, int n_in,
                              void* d_out, int out_size, void* d_ws, size_t ws_size,
                              hipStream_t stream) {
  const float* x = (const float*)d_in[0];
  const float* wqkv = (const float*)d_in[1];
  const float* wout = (const float*)d_in[2];
  float* out = (float*)d_out;
  char* ws = (char*)d_ws;

  u16* xb    = (u16*)(ws);                       //  8 MB
  u16* wqkvb = (u16*)(ws + 8u * 1024 * 1024);    //  6 MB
  u16* woutb = (u16*)(ws + 14u * 1024 * 1024);   //  2 MB
  u16* qkvb  = (u16*)(ws + 16u * 1024 * 1024);   // 24 MB
  u16* ctxb  = (u16*)(ws + 40u * 1024 * 1024);   //  8 MB
  u16* vTb   = (u16*)(ws + 48u * 1024 * 1024);   //  8 MB

  cast_all<<<8192, 256, 0, stream>>>((const float4*)x, (const float4*)wqkv,
                                     (const float4*)wout, (ushort4*)xb);

  // qkv[4096][3072] = xb @ wqkvb^T : fine-interleaved 256x256 kernel
  gemm_bt_256<u16><<<dim3(12, 16), 512, 0, stream>>>(xb, wqkvb, qkvb, 4096, 3072, 1024);

  vtrans<<<dim3(8, N_H, N_B), 256, 0, stream>>>(qkvb, vTb);

  attn_fwd<<<dim3(32, 8), 512, 0, stream>>>(qkvb, vTb, ctxb);

  gemm_bt<float><<<dim3(8, 32), 256, 0, stream>>>(ctxb, woutb, out, 4096, 1024, 1024);
}

// Round 15
// 121.589 us; speedup vs baseline: 1.0990x; 1.0990x over previous
//
#include <hip/hip_runtime.h>

// ---------------------------------------------------------------------------
// MultiheadSelfAttention: x[2,2048,1024] f32, w_qkv[3072,1024] f32,
// w_out[1024,1024] f32 -> out[2,2048,1024] f32.
// cast->bf16; qkv = x @ w_qkv^T (128x128 MFMA GEMM); V pre-transpose;
// causal flash attn (round-7 skeleton, KVBLK=128: 8-wave 128-row blocks,
// paired q-tiles (p,15-p), 17 uniform iters, triple-buffered K/V via
// global_load_lds + counted vmcnt(4), XCD-colocated); out = ctx @ w_out^T.
// ---------------------------------------------------------------------------

typedef short short8 __attribute__((ext_vector_type(8)));
typedef float f32x4 __attribute__((ext_vector_type(4)));
typedef unsigned short u16;
typedef unsigned int u32;

#define T_SEQ 2048
#define N_B 2
#define N_H 16
#define HD 64
#define DM 1024
#define TRIPLE 3072

__device__ __forceinline__ u16 f2bf(float f) {
  union { float f; unsigned u; } v;
  v.f = f;
  unsigned r = v.u + 0x7fffu + ((v.u >> 16) & 1u);
  return (u16)(r >> 16);
}

__device__ __forceinline__ float bf2f(u16 x) {
  return __uint_as_float((u32)x << 16);
}

__device__ __forceinline__ u32 cvtpk(float a, float b) {
  u32 r;
  asm("v_cvt_pk_bf16_f32 %0, %1, %2" : "=v"(r) : "v"(a), "v"(b));
  return r;
}

typedef const __attribute__((address_space(1))) void gvoid;
typedef __attribute__((address_space(3))) void lvoid;

__device__ __forceinline__ void g2l16(const void* g, void* l) {
  __builtin_amdgcn_global_load_lds((gvoid*)g, (lvoid*)l, 16, 0, 0);
}

__device__ __forceinline__ void storeC(float* p, float v) { *p = v; }
__device__ __forceinline__ void storeC(u16* p, float v) { *p = f2bf(v); }

// ---------------------------------------------------------------------------
// fused cast of x | w_qkv | w_out into contiguous bf16 workspace
__global__ __launch_bounds__(256) void cast_all(const float4* __restrict__ x,
                                                const float4* __restrict__ wq,
                                                const float4* __restrict__ wo,
                                                ushort4* __restrict__ out) {
  int i = blockIdx.x * 256 + threadIdx.x;
  const float4* src;
  int off;
  if (i < 1048576) { src = x; off = 0; }
  else if (i < 1835008) { src = wq; off = 1048576; }
  else { src = wo; off = 1835008; }
  float4 v = src[i - off];
  ushort4 o;
  o.x = f2bf(v.x); o.y = f2bf(v.y); o.z = f2bf(v.z); o.w = f2bf(v.w);
  out[i] = o;
}

// ---------------------------------------------------------------------------
// V transpose: qkv[b*T+t][2048 + h*64 + d] -> vT[(b*16+h)*64 + d][t] (bf16).
// ---------------------------------------------------------------------------
__global__ __launch_bounds__(256) void vtrans(const u16* __restrict__ qkv,
                                              u16* __restrict__ vT) {
  const int tid = threadIdx.x;
  const int w = tid >> 6, lane = tid & 63;
  const int ti = lane >> 3, di = lane & 7;
  const int h = blockIdx.y, b = blockIdx.z;
  const int t0 = blockIdx.x * 256 + w * 64 + ti * 8;

  const u16* src = qkv + (size_t)(b * T_SEQ + t0) * TRIPLE + 2 * DM + h * HD + di * 8;
  u32 x[8][4];
#pragma unroll
  for (int e = 0; e < 8; ++e) {
    union { short8 v; u32 u[4]; } cv;
    cv.v = *(const short8*)(src + (size_t)e * TRIPLE);
#pragma unroll
    for (int j = 0; j < 4; ++j) x[e][j] = cv.u[j];
  }
  u32 y[8][4];
#pragma unroll
  for (int a = 0; a < 4; ++a)
#pragma unroll
    for (int j = 0; j < 4; ++j) {
      u32 lo = x[2 * a][j], hi = x[2 * a + 1][j];
      y[2 * a][j] = (lo & 0x0000FFFFu) | (hi << 16);
      y[2 * a + 1][j] = (lo >> 16) | (hi & 0xFFFF0000u);
    }
  u16* dst = vT + ((size_t)(b * N_H + h) * HD + di * 8) * T_SEQ + t0;
#pragma unroll
  for (int dd = 0; dd < 8; ++dd) {
    union { short8 v; u32 u[4]; } cv;
#pragma unroll
    for (int a = 0; a < 4; ++a) cv.u[a] = y[2 * a + (dd & 1)][dd >> 1];
    *(short8*)(dst + (size_t)dd * T_SEQ) = cv.v;
  }
}

// ---------------------------------------------------------------------------
// C[M][N] = A[M][K] * W[N][K]^T  (bf16 in, fp32 acc). 128x128 tile, BK=64.
// ---------------------------------------------------------------------------
template <typename OutT>
__global__ __launch_bounds__(256) void gemm_bt(const u16* __restrict__ A,
                                               const u16* __restrict__ W,
                                               OutT* __restrict__ C,
                                               int M, int N, int K) {
  __shared__ char As[128 * 64 * 2];
  __shared__ char Bs[128 * 64 * 2];
  const int tid = threadIdx.x;
  const int lane = tid & 63, w = tid >> 6;
  const int l15 = lane & 15, l4 = lane >> 4;
  const int m0 = blockIdx.y * 128, n0 = blockIdx.x * 128;
  const int wr = (w >> 1) * 64, wc = (w & 1) * 64;

  const f32x4 zero = {0.f, 0.f, 0.f, 0.f};
  f32x4 acc[4][4];
#pragma unroll
  for (int m = 0; m < 4; ++m)
#pragma unroll
    for (int n = 0; n < 4; ++n) acc[m][n] = zero;

  for (int k0 = 0; k0 < K; k0 += 64) {
#pragma unroll
    for (int i = 0; i < 4; ++i) {
      const int cb = (i * 4 + w) * 64;
      const int c = cb + lane;
      const int row = c >> 3;
      const int ks = ((c & 7) ^ (row & 7)) * 8;
      g2l16(A + (size_t)(m0 + row) * K + k0 + ks, As + (size_t)cb * 16);
      g2l16(W + (size_t)(n0 + row) * K + k0 + ks, Bs + (size_t)cb * 16);
    }
    __syncthreads();

#pragma unroll
    for (int kk = 0; kk < 2; ++kk) {
      short8 a[4], b[4];
#pragma unroll
      for (int m = 0; m < 4; ++m) {
        int row = wr + m * 16 + l15;
        int slot = (kk * 4 + l4) ^ (row & 7);
        a[m] = *(const short8*)(As + row * 128 + slot * 16);
      }
#pragma unroll
      for (int n = 0; n < 4; ++n) {
        int row = wc + n * 16 + l15;
        int slot = (kk * 4 + l4) ^ (row & 7);
        b[n] = *(const short8*)(Bs + row * 128 + slot * 16);
      }
#pragma unroll
      for (int m = 0; m < 4; ++m)
#pragma unroll
        for (int n = 0; n < 4; ++n)
          acc[m][n] = __builtin_amdgcn_mfma_f32_16x16x32_bf16(a[m], b[n], acc[m][n], 0, 0, 0);
    }
    __syncthreads();
  }

#pragma unroll
  for (int m = 0; m < 4; ++m)
#pragma unroll
    for (int n = 0; n < 4; ++n)
#pragma unroll
      for (int r = 0; r < 4; ++r) {
        int row = m0 + wr + m * 16 + l4 * 4 + r;
        int col = n0 + wc + n * 16 + l15;
        storeC(C + (size_t)row * N + col, acc[m][n][r]);
      }
}

// ---------------------------------------------------------------------------
// Causal flash attention, KVBLK=128. 8-wave blocks, 128 q-rows per pass,
// paired q-tiles (p, 15-p). Pass A: kt = 0..p ascending (diag last).
// Pass B: kt = 16-i descending (diag 15-p first). 17 iterations for every
// block; at step i all blocks of a (b,h) read tile i or 16-i.
// Triple-buffered K/V staged by global_load_lds with 2-deep prefetch;
// barriers use counted vmcnt(4). Grid: x = (b,h) group (XCD coloc), y = p.
// ---------------------------------------------------------------------------
__global__ __launch_bounds__(512) void attn_fwd(const u16* __restrict__ qkv,
                                                const u16* __restrict__ vT,
                                                u16* __restrict__ ctx) {
  __shared__ char Ks[3][16384];  // K tile [128 key][8 slots x 16B], slot=c^(key&7)
  __shared__ char Vs[3][16384];  // V^T tile [64 d][16 slots x 16B], slot=c^(d&7)
  __shared__ char Pl[8][4096];   // per-wave P [16 q][128 key], swizzled

  const int tid = threadIdx.x;
  const int lane = tid & 63, w = tid >> 6;        // w in 0..7
  const int l15 = lane & 15, l4 = lane >> 4;
  const int g = blockIdx.x;                       // b*16+h : same-XCD group
  const int p = blockIdx.y;                       // 0..7
  const int h = g & 15, b = g >> 4;
  const int q0A = 128 * p, q0B = 128 * (15 - p);

  // ---- preload Q for BOTH passes, prescaled by 0.125*log2(e) ----
  const float c_log2 = 0.18033688011112042f;
  short8 qa2[2][2];
#pragma unroll
  for (int ps = 0; ps < 2; ++ps) {
    const int qq0 = ps ? q0B : q0A;
    const u16* qp = qkv + (size_t)(b * T_SEQ + qq0 + w * 16 + l15) * TRIPLE + h * HD;
#pragma unroll
    for (int kk = 0; kk < 2; ++kk) {
      short8 raw = *(const short8*)(qp + kk * 32 + l4 * 8);
      union { short8 v; u32 w4[4]; } qq;
#pragma unroll
      for (int j = 0; j < 4; ++j)
        qq.w4[j] = cvtpk(bf2f((u16)raw[2 * j]) * c_log2,
                         bf2f((u16)raw[2 * j + 1]) * c_log2);
      qa2[ps][kk] = qq.v;
    }
  }

  // ---- staging bases (pre-swizzled source, linear LDS dest) ----
  // K: chunk c in [0,1024): key = c>>3, src k-chunk = (c&7)^(key&7)
  const int kr = tid >> 3;                        // 0..63; round 1 adds 64
  const int kswz = ((tid & 7) ^ (kr & 7)) << 3;
  const u16* kbase = qkv + (size_t)(b * T_SEQ + kr) * TRIPLE + DM + h * HD + kswz;
  // V: chunk c in [0,1024): d = c>>4, src key-chunk = (c&15)^(d&7)
  const int vd = tid >> 4;                        // 0..31; round 1 adds 32
  const int vswz = ((tid & 15) ^ (vd & 7)) << 3;
  const u16* vbase = vT + ((size_t)g * HD + vd) * T_SEQ + vswz;

#define STAGE(kt_, buf_)                                                      \
  {                                                                           \
    g2l16(kbase + (size_t)((kt_) * 128) * TRIPLE, Ks[buf_] + tid * 16);       \
    g2l16(kbase + (size_t)((kt_) * 128 + 64) * TRIPLE,                        \
          Ks[buf_] + (512 + tid) * 16);                                       \
    g2l16(vbase + (u32)((kt_) * 128), Vs[buf_] + tid * 16);                   \
    g2l16(vbase + (size_t)32 * T_SEQ + (u32)((kt_) * 128),                    \
          Vs[buf_] + (512 + tid) * 16);                                       \
  }

  char* Plb = Pl[w];

  const f32x4 zero = {0.f, 0.f, 0.f, 0.f};
  f32x4 o[4];
#pragma unroll
  for (int nt = 0; nt < 4; ++nt) o[nt] = zero;
  float mr = -INFINITY, lr = 0.f;
  short8 qa0 = qa2[0][0], qa1 = qa2[0][1];
  int q0 = q0A;

  // ---- prologue: stage tiles for i=0,1 into bufs 0,1; wait stage0 only ----
  STAGE(0, 0);
  {
    const int kt1 = (1 <= p) ? 1 : 15;
    STAGE(kt1, 1);
  }
  asm volatile("s_waitcnt vmcnt(4)\n\ts_barrier" ::: "memory");

  int cur = 0;
  for (int i = 0;; ++i) {
    const int kt = (i <= p) ? i : 16 - i;

    // ---- issue 2-ahead prefetch into buf (cur+2)%3 ----
    if (i + 2 <= 16) {
      const int kt2 = (i + 2 <= p) ? (i + 2) : 14 - i;
      int sb = cur - 1;
      if (sb < 0) sb = 2;
      STAGE(kt2, sb);
    }

    const int k0 = kt * 128;
    // wave-active guard: skip tiles entirely above this wave's q-band
    if (k0 <= q0 + w * 16) {
      // ---- S^T = K Q^T : lane holds S[key=mt*16+l4*4+r][q=l15] ----
      f32x4 s[8];
#pragma unroll
      for (int mt = 0; mt < 8; ++mt) s[mt] = zero;
      __builtin_amdgcn_s_setprio(1);
#pragma unroll
      for (int mt = 0; mt < 8; ++mt) {
        int row = mt * 16 + l15;                 // key within tile, 0..127
        int slot0 = l4 ^ (row & 7);
        short8 kb0 = *(const short8*)(Ks[cur] + row * 128 + slot0 * 16);
        s[mt] = __builtin_amdgcn_mfma_f32_16x16x32_bf16(kb0, qa0, s[mt], 0, 0, 0);
        int slot1 = (4 + l4) ^ (row & 7);
        short8 kb1 = *(const short8*)(Ks[cur] + row * 128 + slot1 * 16);
        s[mt] = __builtin_amdgcn_mfma_f32_16x16x32_bf16(kb1, qa1, s[mt], 0, 0, 0);
      }
      __builtin_amdgcn_s_setprio(0);

      // causal mask on the two diagonal iterations (A diag i==p, B diag i==p+1)
      if (i == p || i == p + 1) {
        const int qrow = q0 + w * 16 + l15;
#pragma unroll
        for (int mt = 0; mt < 8; ++mt)
#pragma unroll
          for (int r = 0; r < 4; ++r) {
            int key = k0 + mt * 16 + l4 * 4 + r;
            if (key > qrow) s[mt][r] = -INFINITY;
          }
      }

      // ---- online softmax, defer-max (THR = 8 in log2 units) ----
      float tA = fmaxf(s[0][0], s[1][0]), tB = fmaxf(s[0][1], s[1][1]);
      float tC = fmaxf(s[0][2], s[1][2]), tD = fmaxf(s[0][3], s[1][3]);
#pragma unroll
      for (int mt = 2; mt < 8; ++mt) {
        tA = fmaxf(tA, s[mt][0]);
        tB = fmaxf(tB, s[mt][1]);
        tC = fmaxf(tC, s[mt][2]);
        tD = fmaxf(tD, s[mt][3]);
      }
      float mx = fmaxf(fmaxf(tA, tB), fmaxf(tC, tD));
      mx = fmaxf(mx, __shfl_xor(mx, 16));
      mx = fmaxf(mx, __shfl_xor(mx, 32));
      if (!__all(mx - mr <= 8.0f)) {
        float mn = fmaxf(mr, mx);
        float fr = exp2f(mr - mn);   // 0 on first active tile of a pass
        lr *= fr;
#pragma unroll
        for (int r = 0; r < 4; ++r) {
          float frq = __shfl(fr, l4 * 4 + r);
#pragma unroll
          for (int nt = 0; nt < 4; ++nt) o[nt][r] *= frq;
        }
        mr = mn;
      }
      float ps = 0.f;
#pragma unroll
      for (int mt = 0; mt < 8; ++mt)
#pragma unroll
        for (int r = 0; r < 4; ++r) {
          float pv = exp2f(s[mt][r] - mr);
          s[mt][r] = pv;
          ps += pv;
        }
      lr += ps;   // per-lane partial; reduced at pass epilogue

      // ---- P -> per-wave LDS (cvt_pk + b64 writes), row stride 256 B ----
#pragma unroll
      for (int mt = 0; mt < 8; ++mt) {
        uint2 pw;
        pw.x = cvtpk(s[mt][0], s[mt][1]);
        pw.y = cvtpk(s[mt][2], s[mt][3]);
        int sc = (mt * 2 + (l4 >> 1)) ^ (l15 & 7);   // 16 chunks, XOR low 3 bits
        *(uint2*)(Plb + l15 * 256 + (sc << 4) + ((l4 & 1) << 3)) = pw;
      }

      // ---- PV: o[q][d] += P[q][key] * V^T[d][key], 4 key-slices of 32 ----
      __builtin_amdgcn_s_setprio(1);
#pragma unroll
      for (int kk = 0; kk < 4; ++kk) {
        int pc = (kk * 4 + l4) ^ (l15 & 7);
        short8 pa = *(const short8*)(Plb + l15 * 256 + (pc << 4));
#pragma unroll
        for (int nt = 0; nt < 4; ++nt) {
          int d = nt * 16 + l15;
          int vc = (kk * 4 + l4) ^ (d & 7);
          short8 vb = *(const short8*)(Vs[cur] + d * 256 + (vc << 4));
          o[nt] = __builtin_amdgcn_mfma_f32_16x16x32_bf16(pa, vb, o[nt], 0, 0, 0);
        }
      }
      __builtin_amdgcn_s_setprio(0);
    }

    // ---- pass epilogues (A diag i==p: write+reset; i==16: write+exit) ----
    if (i == p || i == 16) {
      lr += __shfl_xor(lr, 16);
      lr += __shfl_xor(lr, 32);
#pragma unroll
      for (int r = 0; r < 4; ++r) {
        float lrq = __shfl(lr, l4 * 4 + r);
        float inv = __builtin_amdgcn_rcpf(lrq);
        size_t t = (size_t)(b * T_SEQ + q0 + w * 16 + l4 * 4 + r);
#pragma unroll
        for (int nt = 0; nt < 4; ++nt)
          ctx[t * DM + h * HD + nt * 16 + l15] = f2bf(o[nt][r] * inv);
      }
      if (i == 16) break;
      // reset for pass B (diag-first, descending)
#pragma unroll
      for (int nt = 0; nt < 4; ++nt) o[nt] = zero;
      mr = -INFINITY; lr = 0.f;
      qa0 = qa2[1][0]; qa1 = qa2[1][1];
      q0 = q0B;
    }

    // ---- counted-vmcnt barrier: newest stage (4 loads) stays in flight ----
    if (i == 15)
      asm volatile("s_waitcnt vmcnt(0)\n\ts_barrier" ::: "memory");
    else
      asm volatile("s_waitcnt vmcnt(4)\n\ts_barrier" ::: "memory");
    cur = (cur == 2) ? 0 : cur + 1;
  }
#undef STAGE
}

// ---------------------------------------------------------------------------
extern "C" void kernel_launch(void* const* d_in, const int* in_sizes, int n_in,
                              void* d_out, int out_size, void* d_ws, size_t ws_size,
                              hipStream_t stream) {
  const float* x = (const float*)d_in[0];
  const float* wqkv = (const float*)d_in[1];
  const float* wout = (const float*)d_in[2];
  float* out = (float*)d_out;
  char* ws = (char*)d_ws;

  u16* xb    = (u16*)(ws);                       //  8 MB
  u16* wqkvb = (u16*)(ws + 8u * 1024 * 1024);    //  6 MB
  u16* woutb = (u16*)(ws + 14u * 1024 * 1024);   //  2 MB
  u16* qkvb  = (u16*)(ws + 16u * 1024 * 1024);   // 24 MB
  u16* ctxb  = (u16*)(ws + 40u * 1024 * 1024);   //  8 MB
  u16* vTb   = (u16*)(ws + 48u * 1024 * 1024);   //  8 MB

  cast_all<<<8192, 256, 0, stream>>>((const float4*)x, (const float4*)wqkv,
                                     (const float4*)wout, (ushort4*)xb);

  gemm_bt<u16><<<dim3(24, 32), 256, 0, stream>>>(xb, wqkvb, qkvb, 4096, 3072, 1024);

  vtrans<<<dim3(8, N_H, N_B), 256, 0, stream>>>(qkvb, vTb);

  attn_fwd<<<dim3(32, 8), 512, 0, stream>>>(qkvb, vTb, ctxb);

  gemm_bt<float><<<dim3(8, 32), 256, 0, stream>>>(ctxb, woutb, out, 4096, 1024, 1024);
}

// Round 16
// 117.828 us; speedup vs baseline: 1.1341x; 1.0319x over previous
//
#include <hip/hip_runtime.h>

// ---------------------------------------------------------------------------
// MultiheadSelfAttention: x[2,2048,1024] f32, w_qkv[3072,1024] f32,
// w_out[1024,1024] f32 -> out[2,2048,1024] f32.
// cast->bf16; qkv = x @ w_qkv^T (128x128 MFMA GEMM, XCD-swizzled);
// V pre-transpose; causal flash attn (KVBLK=128, 8-wave 128-row blocks,
// paired q-tiles (p,15-p), 17 uniform iters, triple-buffered K/V via
// global_load_lds + counted vmcnt(4), half-tile 128B-row V/P layouts);
// out = ctx @ w_out^T. fp32 accumulation.
// ---------------------------------------------------------------------------

typedef short short8 __attribute__((ext_vector_type(8)));
typedef float f32x4 __attribute__((ext_vector_type(4)));
typedef unsigned short u16;
typedef unsigned int u32;

#define T_SEQ 2048
#define N_B 2
#define N_H 16
#define HD 64
#define DM 1024
#define TRIPLE 3072

__device__ __forceinline__ u16 f2bf(float f) {
  union { float f; unsigned u; } v;
  v.f = f;
  unsigned r = v.u + 0x7fffu + ((v.u >> 16) & 1u);
  return (u16)(r >> 16);
}

__device__ __forceinline__ float bf2f(u16 x) {
  return __uint_as_float((u32)x << 16);
}

__device__ __forceinline__ u32 cvtpk(float a, float b) {
  u32 r;
  asm("v_cvt_pk_bf16_f32 %0, %1, %2" : "=v"(r) : "v"(a), "v"(b));
  return r;
}

typedef const __attribute__((address_space(1))) void gvoid;
typedef __attribute__((address_space(3))) void lvoid;

__device__ __forceinline__ void g2l16(const void* g, void* l) {
  __builtin_amdgcn_global_load_lds((gvoid*)g, (lvoid*)l, 16, 0, 0);
}

__device__ __forceinline__ void storeC(float* p, float v) { *p = v; }
__device__ __forceinline__ void storeC(u16* p, float v) { *p = f2bf(v); }

// ---------------------------------------------------------------------------
// fused cast of x | w_qkv | w_out into contiguous bf16 workspace
__global__ __launch_bounds__(256) void cast_all(const float4* __restrict__ x,
                                                const float4* __restrict__ wq,
                                                const float4* __restrict__ wo,
                                                ushort4* __restrict__ out) {
  int i = blockIdx.x * 256 + threadIdx.x;
  const float4* src;
  int off;
  if (i < 1048576) { src = x; off = 0; }
  else if (i < 1835008) { src = wq; off = 1048576; }
  else { src = wo; off = 1835008; }
  float4 v = src[i - off];
  ushort4 o;
  o.x = f2bf(v.x); o.y = f2bf(v.y); o.z = f2bf(v.z); o.w = f2bf(v.w);
  out[i] = o;
}

// ---------------------------------------------------------------------------
// V transpose: qkv[b*T+t][2048 + h*64 + d] -> vT[(b*16+h)*64 + d][t] (bf16).
// ---------------------------------------------------------------------------
__global__ __launch_bounds__(256) void vtrans(const u16* __restrict__ qkv,
                                              u16* __restrict__ vT) {
  const int tid = threadIdx.x;
  const int w = tid >> 6, lane = tid & 63;
  const int ti = lane >> 3, di = lane & 7;
  const int h = blockIdx.y, b = blockIdx.z;
  const int t0 = blockIdx.x * 256 + w * 64 + ti * 8;

  const u16* src = qkv + (size_t)(b * T_SEQ + t0) * TRIPLE + 2 * DM + h * HD + di * 8;
  u32 x[8][4];
#pragma unroll
  for (int e = 0; e < 8; ++e) {
    union { short8 v; u32 u[4]; } cv;
    cv.v = *(const short8*)(src + (size_t)e * TRIPLE);
#pragma unroll
    for (int j = 0; j < 4; ++j) x[e][j] = cv.u[j];
  }
  u32 y[8][4];
#pragma unroll
  for (int a = 0; a < 4; ++a)
#pragma unroll
    for (int j = 0; j < 4; ++j) {
      u32 lo = x[2 * a][j], hi = x[2 * a + 1][j];
      y[2 * a][j] = (lo & 0x0000FFFFu) | (hi << 16);
      y[2 * a + 1][j] = (lo >> 16) | (hi & 0xFFFF0000u);
    }
  u16* dst = vT + ((size_t)(b * N_H + h) * HD + di * 8) * T_SEQ + t0;
#pragma unroll
  for (int dd = 0; dd < 8; ++dd) {
    union { short8 v; u32 u[4]; } cv;
#pragma unroll
    for (int a = 0; a < 4; ++a) cv.u[a] = y[2 * a + (dd & 1)][dd >> 1];
    *(short8*)(dst + (size_t)dd * T_SEQ) = cv.v;
  }
}

// ---------------------------------------------------------------------------
// C[M][N] = A[M][K] * W[N][K]^T  (bf16 in, fp32 acc). 128x128 tile, BK=64.
// Bijective XCD swizzle on the block id (requires nwg % 8 == 0).
// ---------------------------------------------------------------------------
template <typename OutT>
__global__ __launch_bounds__(256) void gemm_bt(const u16* __restrict__ A,
                                               const u16* __restrict__ W,
                                               OutT* __restrict__ C,
                                               int M, int N, int K) {
  __shared__ char As[128 * 64 * 2];
  __shared__ char Bs[128 * 64 * 2];
  const int tid = threadIdx.x;
  const int lane = tid & 63, w = tid >> 6;
  const int l15 = lane & 15, l4 = lane >> 4;

  // XCD-aware block remap: id = (wg%8)*(nwg/8) + wg/8
  const int wg = blockIdx.x + gridDim.x * blockIdx.y;
  const int nwg = gridDim.x * gridDim.y;
  const int id = (wg & 7) * (nwg >> 3) + (wg >> 3);
  const int m0 = (id / gridDim.x) * 128, n0 = (id % gridDim.x) * 128;

  const int wr = (w >> 1) * 64, wc = (w & 1) * 64;

  const f32x4 zero = {0.f, 0.f, 0.f, 0.f};
  f32x4 acc[4][4];
#pragma unroll
  for (int m = 0; m < 4; ++m)
#pragma unroll
    for (int n = 0; n < 4; ++n) acc[m][n] = zero;

  for (int k0 = 0; k0 < K; k0 += 64) {
#pragma unroll
    for (int i = 0; i < 4; ++i) {
      const int cb = (i * 4 + w) * 64;
      const int c = cb + lane;
      const int row = c >> 3;
      const int ks = ((c & 7) ^ (row & 7)) * 8;
      g2l16(A + (size_t)(m0 + row) * K + k0 + ks, As + (size_t)cb * 16);
      g2l16(W + (size_t)(n0 + row) * K + k0 + ks, Bs + (size_t)cb * 16);
    }
    __syncthreads();

#pragma unroll
    for (int kk = 0; kk < 2; ++kk) {
      short8 a[4], b[4];
#pragma unroll
      for (int m = 0; m < 4; ++m) {
        int row = wr + m * 16 + l15;
        int slot = (kk * 4 + l4) ^ (row & 7);
        a[m] = *(const short8*)(As + row * 128 + slot * 16);
      }
#pragma unroll
      for (int n = 0; n < 4; ++n) {
        int row = wc + n * 16 + l15;
        int slot = (kk * 4 + l4) ^ (row & 7);
        b[n] = *(const short8*)(Bs + row * 128 + slot * 16);
      }
#pragma unroll
      for (int m = 0; m < 4; ++m)
#pragma unroll
        for (int n = 0; n < 4; ++n)
          acc[m][n] = __builtin_amdgcn_mfma_f32_16x16x32_bf16(a[m], b[n], acc[m][n], 0, 0, 0);
    }
    __syncthreads();
  }

#pragma unroll
  for (int m = 0; m < 4; ++m)
#pragma unroll
    for (int n = 0; n < 4; ++n)
#pragma unroll
      for (int r = 0; r < 4; ++r) {
        int row = m0 + wr + m * 16 + l4 * 4 + r;
        int col = n0 + wc + n * 16 + l15;
        storeC(C + (size_t)row * N + col, acc[m][n][r]);
      }
}

// ---------------------------------------------------------------------------
// Causal flash attention, KVBLK=128, half-tile 128B-row V/P layouts.
// 8-wave blocks, 128 q-rows per pass, paired q-tiles (p, 15-p). Pass A:
// kt = 0..p ascending (diag last). Pass B: kt = 16-i descending (diag first).
// 17 iterations for every block; at step i all blocks of a (b,h) read tile
// i or 16-i. Triple-buffered K/V staged by global_load_lds with 2-deep
// prefetch; barriers use counted vmcnt(4). Grid: x = (b,h) group, y = p.
// ---------------------------------------------------------------------------
__global__ __launch_bounds__(512) void attn_fwd(const u16* __restrict__ qkv,
                                                const u16* __restrict__ vT,
                                                u16* __restrict__ ctx) {
  __shared__ char Ks[3][16384];  // K tile [128 key][8 slots x16B], slot=c^(key&7)
  __shared__ char Vs[3][16384];  // V^T [2 kh][64 d][8 slots x16B], slot=c^(d&7)
  __shared__ char Pl[8][4096];   // per-wave P [2 kh][16 q][64 key], swizzled

  const int tid = threadIdx.x;
  const int lane = tid & 63, w = tid >> 6;        // w in 0..7
  const int l15 = lane & 15, l4 = lane >> 4;
  const int g = blockIdx.x;                       // b*16+h : same-XCD group
  const int p = blockIdx.y;                       // 0..7
  const int h = g & 15, b = g >> 4;
  const int q0A = 128 * p, q0B = 128 * (15 - p);

  // ---- preload Q for BOTH passes, prescaled by 0.125*log2(e) ----
  const float c_log2 = 0.18033688011112042f;
  short8 qa2[2][2];
#pragma unroll
  for (int ps = 0; ps < 2; ++ps) {
    const int qq0 = ps ? q0B : q0A;
    const u16* qp = qkv + (size_t)(b * T_SEQ + qq0 + w * 16 + l15) * TRIPLE + h * HD;
#pragma unroll
    for (int kk = 0; kk < 2; ++kk) {
      short8 raw = *(const short8*)(qp + kk * 32 + l4 * 8);
      union { short8 v; u32 w4[4]; } qq;
#pragma unroll
      for (int j = 0; j < 4; ++j)
        qq.w4[j] = cvtpk(bf2f((u16)raw[2 * j]) * c_log2,
                         bf2f((u16)raw[2 * j + 1]) * c_log2);
      qa2[ps][kk] = qq.v;
    }
  }

  // ---- staging bases (pre-swizzled source, linear LDS dest) ----
  // K: chunk c in [0,1024): key = c>>3 (0..127), src k-chunk = (c&7)^(key&7)
  const int kr = tid >> 3;                        // 0..63; second chunk +64
  const int kswz = ((tid & 7) ^ (kr & 7)) << 3;
  const u16* kbase = qkv + (size_t)(b * T_SEQ + kr) * TRIPLE + DM + h * HD + kswz;
  // V half: chunk c in [0,512): d = c>>3 (0..63), src key-chunk = (c&7)^(d&7)
  const int vd = tid >> 3;                        // 0..63
  const int vswz = ((tid & 7) ^ (vd & 7)) << 3;
  const u16* vbase = vT + ((size_t)g * HD + vd) * T_SEQ + vswz;

#define STAGE(kt_, buf_)                                                      \
  {                                                                           \
    g2l16(kbase + (size_t)((kt_) * 128) * TRIPLE, Ks[buf_] + tid * 16);       \
    g2l16(kbase + (size_t)((kt_) * 128 + 64) * TRIPLE,                        \
          Ks[buf_] + (512 + tid) * 16);                                       \
    g2l16(vbase + (u32)((kt_) * 128), Vs[buf_] + tid * 16);                   \
    g2l16(vbase + (u32)((kt_) * 128 + 64), Vs[buf_] + 8192 + tid * 16);       \
  }

  char* Plb = Pl[w];

  const f32x4 zero = {0.f, 0.f, 0.f, 0.f};
  f32x4 o[4];
#pragma unroll
  for (int nt = 0; nt < 4; ++nt) o[nt] = zero;
  float mr = -INFINITY, lr = 0.f;
  short8 qa0 = qa2[0][0], qa1 = qa2[0][1];
  int q0 = q0A;

  // ---- prologue: stage tiles for i=0,1 into bufs 0,1; wait stage0 only ----
  STAGE(0, 0);
  {
    const int kt1 = (1 <= p) ? 1 : 15;
    STAGE(kt1, 1);
  }
  asm volatile("s_waitcnt vmcnt(4)\n\ts_barrier" ::: "memory");

  int cur = 0;
  for (int i = 0;; ++i) {
    const int kt = (i <= p) ? i : 16 - i;

    // ---- issue 2-ahead prefetch into buf (cur+2)%3 ----
    if (i + 2 <= 16) {
      const int kt2 = (i + 2 <= p) ? (i + 2) : 14 - i;
      int sb = cur - 1;
      if (sb < 0) sb = 2;
      STAGE(kt2, sb);
    }

    const int k0 = kt * 128;
    // wave-active guard: skip tiles entirely above this wave's q-band
    if (k0 <= q0 + w * 16) {
      // ---- S^T = K Q^T : lane holds S[key=mt*16+l4*4+r][q=l15] ----
      f32x4 s[8];
#pragma unroll
      for (int mt = 0; mt < 8; ++mt) s[mt] = zero;
      __builtin_amdgcn_s_setprio(1);
#pragma unroll
      for (int mt = 0; mt < 8; ++mt) {
        int row = mt * 16 + l15;                 // key within tile, 0..127
        int slot0 = l4 ^ (row & 7);
        short8 kb0 = *(const short8*)(Ks[cur] + row * 128 + slot0 * 16);
        s[mt] = __builtin_amdgcn_mfma_f32_16x16x32_bf16(kb0, qa0, s[mt], 0, 0, 0);
        int slot1 = (4 + l4) ^ (row & 7);
        short8 kb1 = *(const short8*)(Ks[cur] + row * 128 + slot1 * 16);
        s[mt] = __builtin_amdgcn_mfma_f32_16x16x32_bf16(kb1, qa1, s[mt], 0, 0, 0);
      }
      __builtin_amdgcn_s_setprio(0);

      // causal mask on the two diagonal iterations (A diag i==p, B diag i==p+1)
      if (i == p || i == p + 1) {
        const int qrow = q0 + w * 16 + l15;
#pragma unroll
        for (int mt = 0; mt < 8; ++mt)
#pragma unroll
          for (int r = 0; r < 4; ++r) {
            int key = k0 + mt * 16 + l4 * 4 + r;
            if (key > qrow) s[mt][r] = -INFINITY;
          }
      }

      // ---- online softmax, defer-max (THR = 8 in log2 units) ----
      float tA = fmaxf(s[0][0], s[1][0]), tB = fmaxf(s[0][1], s[1][1]);
      float tC = fmaxf(s[0][2], s[1][2]), tD = fmaxf(s[0][3], s[1][3]);
#pragma unroll
      for (int mt = 2; mt < 8; ++mt) {
        tA = fmaxf(tA, s[mt][0]);
        tB = fmaxf(tB, s[mt][1]);
        tC = fmaxf(tC, s[mt][2]);
        tD = fmaxf(tD, s[mt][3]);
      }
      float mx = fmaxf(fmaxf(tA, tB), fmaxf(tC, tD));
      mx = fmaxf(mx, __shfl_xor(mx, 16));
      mx = fmaxf(mx, __shfl_xor(mx, 32));
      if (!__all(mx - mr <= 8.0f)) {
        float mn = fmaxf(mr, mx);
        float fr = exp2f(mr - mn);   // 0 on first active tile of a pass
        lr *= fr;
#pragma unroll
        for (int r = 0; r < 4; ++r) {
          float frq = __shfl(fr, l4 * 4 + r);
#pragma unroll
          for (int nt = 0; nt < 4; ++nt) o[nt][r] *= frq;
        }
        mr = mn;
      }
      float ps = 0.f;
#pragma unroll
      for (int mt = 0; mt < 8; ++mt)
#pragma unroll
        for (int r = 0; r < 4; ++r) {
          float pv = exp2f(s[mt][r] - mr);
          s[mt][r] = pv;
          ps += pv;
        }
      lr += ps;   // per-lane partial; reduced at pass epilogue

      // ---- P -> per-wave LDS (cvt_pk + b64 writes), two 128B-row halves ----
#pragma unroll
      for (int mt = 0; mt < 8; ++mt) {
        const int kh = mt >> 2, m4 = mt & 3;
        uint2 pw;
        pw.x = cvtpk(s[mt][0], s[mt][1]);
        pw.y = cvtpk(s[mt][2], s[mt][3]);
        int slot = ((m4 * 2 + (l4 >> 1)) ^ (l15 & 7));
        *(uint2*)(Plb + kh * 2048 + l15 * 128 + (slot << 4) + ((l4 & 1) << 3)) = pw;
      }

      // ---- PV: o[q][d] += P[q][key] * V^T[d][key], 4 key-slices of 32 ----
      __builtin_amdgcn_s_setprio(1);
#pragma unroll
      for (int kk = 0; kk < 4; ++kk) {
        const int kh = kk >> 1, k2 = kk & 1;
        int pc = (k2 * 4 + l4) ^ (l15 & 7);
        short8 pa = *(const short8*)(Plb + kh * 2048 + l15 * 128 + (pc << 4));
#pragma unroll
        for (int nt = 0; nt < 4; ++nt) {
          int d = nt * 16 + l15;
          int vc = (k2 * 4 + l4) ^ (d & 7);
          short8 vb = *(const short8*)(Vs[cur] + kh * 8192 + d * 128 + (vc << 4));
          o[nt] = __builtin_amdgcn_mfma_f32_16x16x32_bf16(pa, vb, o[nt], 0, 0, 0);
        }
      }
      __builtin_amdgcn_s_setprio(0);
    }

    // ---- pass epilogues (A diag i==p: write+reset; i==16: write+exit) ----
    if (i == p || i == 16) {
      lr += __shfl_xor(lr, 16);
      lr += __shfl_xor(lr, 32);
#pragma unroll
      for (int r = 0; r < 4; ++r) {
        float lrq = __shfl(lr, l4 * 4 + r);
        float inv = __builtin_amdgcn_rcpf(lrq);
        size_t t = (size_t)(b * T_SEQ + q0 + w * 16 + l4 * 4 + r);
#pragma unroll
        for (int nt = 0; nt < 4; ++nt)
          ctx[t * DM + h * HD + nt * 16 + l15] = f2bf(o[nt][r] * inv);
      }
      if (i == 16) break;
      // reset for pass B (diag-first, descending)
#pragma unroll
      for (int nt = 0; nt < 4; ++nt) o[nt] = zero;
      mr = -INFINITY; lr = 0.f;
      qa0 = qa2[1][0]; qa1 = qa2[1][1];
      q0 = q0B;
    }

    // ---- counted-vmcnt barrier: newest stage (4 loads) stays in flight ----
    if (i == 15)
      asm volatile("s_waitcnt vmcnt(0)\n\ts_barrier" ::: "memory");
    else
      asm volatile("s_waitcnt vmcnt(4)\n\ts_barrier" ::: "memory");
    cur = (cur == 2) ? 0 : cur + 1;
  }
#undef STAGE
}

// ---------------------------------------------------------------------------
extern "C" void kernel_launch(void* const* d_in, const int* in_sizes, int n_in,
                              void* d_out, int out_size, void* d_ws, size_t ws_size,
                              hipStream_t stream) {
  const float* x = (const float*)d_in[0];
  const float* wqkv = (const float*)d_in[1];
  const float* wout = (const float*)d_in[2];
  float* out = (float*)d_out;
  char* ws = (char*)d_ws;

  u16* xb    = (u16*)(ws);                       //  8 MB
  u16* wqkvb = (u16*)(ws + 8u * 1024 * 1024);    //  6 MB
  u16* woutb = (u16*)(ws + 14u * 1024 * 1024);   //  2 MB
  u16* qkvb  = (u16*)(ws + 16u * 1024 * 1024);   // 24 MB
  u16* ctxb  = (u16*)(ws + 40u * 1024 * 1024);   //  8 MB
  u16* vTb   = (u16*)(ws + 48u * 1024 * 1024);   //  8 MB

  cast_all<<<8192, 256, 0, stream>>>((const float4*)x, (const float4*)wqkv,
                                     (const float4*)wout, (ushort4*)xb);

  gemm_bt<u16><<<dim3(24, 32), 256, 0, stream>>>(xb, wqkvb, qkvb, 4096, 3072, 1024);

  vtrans<<<dim3(8, N_H, N_B), 256, 0, stream>>>(qkvb, vTb);

  attn_fwd<<<dim3(32, 8), 512, 0, stream>>>(qkvb, vTb, ctxb);

  gemm_bt<float><<<dim3(8, 32), 256, 0, stream>>>(ctxb, woutb, out, 4096, 1024, 1024);
}